// Round 2
// baseline (1447.349 us; speedup 1.0000x reference)
//
#include <hip/hip_runtime.h>
#include <hip/hip_bf16.h>
#include <stdint.h>

#define DIM   512
#define BATCH 64
#define KENC  1024          // encoded K layout per row: [hi(512) | lo(512)]
#define BM    128
#define BN    128
#define BKE   64            // K-tile width (bf16 elements)
#define NKT   24            // 3 phases * 8 tiles (K_eff = 1536)

typedef __attribute__((ext_vector_type(8))) short short8;   // 8 bf16 = 4 VGPRs
typedef __attribute__((ext_vector_type(4))) float floatx4;

__device__ __forceinline__ ushort f2bf(float f) {
    __hip_bfloat16 h = __float2bfloat16(f);
    return *(ushort*)&h;
}
__device__ __forceinline__ float bf2f(ushort u) {
    __hip_bfloat16 h = *(__hip_bfloat16*)&u;
    return (float)h;
}

// async global->LDS, 16B per lane. HW semantics: LDS base is wave-uniform
// (first lane's ptr), lane i lands at base + i*16 -- our chunk layout matches.
typedef __attribute__((address_space(3))) uint32_t lds_u32;
typedef const __attribute__((address_space(1))) uint32_t glb_u32;
__device__ __forceinline__ void gload16(const ushort* g, ushort* l) {
    __builtin_amdgcn_global_load_lds((glb_u32*)g, (lds_u32*)l, 16, 0, 0);
}

// ---------------- kernel 1: per-matrix Frobenius norm ----------------
__global__ __launch_bounds__(256) void normA_kernel(const float* __restrict__ x,
                                                    float* __restrict__ norms) {
    int b = blockIdx.x;
    const float4* xv = (const float4*)(x + (size_t)b * DIM * DIM);
    float s = 0.f;
    for (int i = threadIdx.x; i < DIM * DIM / 4; i += 256) {
        float4 v = xv[i];
        s += v.x * v.x + v.y * v.y + v.z * v.z + v.w * v.w;
    }
    #pragma unroll
    for (int off = 32; off > 0; off >>= 1) s += __shfl_down(s, off, 64);
    __shared__ float red[4];
    int lane = threadIdx.x & 63, wid = threadIdx.x >> 6;
    if (lane == 0) red[wid] = s;
    __syncthreads();
    if (threadIdx.x == 0) norms[b] = sqrtf(red[0] + red[1] + red[2] + red[3]);
}

// -------- kernel 2: encode Y0 = x/normA -> Yenc ; T1 = 1.5I - 0.5*Y0 -> Tenc (Z1 aliases T1) --------
__global__ __launch_bounds__(256) void init_kernel(const float* __restrict__ x,
                                                   const float* __restrict__ norms,
                                                   ushort* __restrict__ Yenc,
                                                   ushort* __restrict__ Tenc) {
    int b = blockIdx.y;
    float inv = 1.0f / norms[b];
    int idx = (blockIdx.x * 256 + threadIdx.x) * 4;  // element index in matrix
    int r = idx >> 9;
    int c = idx & 511;
    float4 v = *(const float4*)(x + (size_t)b * DIM * DIM + idx);
    float yv[4] = {v.x * inv, v.y * inv, v.z * inv, v.w * inv};
    size_t base = (size_t)b * DIM * KENC + (size_t)r * KENC;
    ushort yhi[4], ylo[4], thi[4], tlo[4];
    #pragma unroll
    for (int j = 0; j < 4; ++j) {
        float y = yv[j];
        yhi[j] = f2bf(y);
        ylo[j] = f2bf(y - bf2f(yhi[j]));
        float t = ((c + j) == r ? 1.5f : 0.0f) - 0.5f * y;
        thi[j] = f2bf(t);
        tlo[j] = f2bf(t - bf2f(thi[j]));
    }
    *(ushort4*)(Yenc + base + c)       = *(ushort4*)yhi;
    *(ushort4*)(Yenc + base + 512 + c) = *(ushort4*)ylo;
    *(ushort4*)(Tenc + base + c)       = *(ushort4*)thi;
    *(ushort4*)(Tenc + base + 512 + c) = *(ushort4*)tlo;
}

// ------- batched split-bf16 NT-GEMM: C = (Ahi+Alo)*(Bhi+Blo)^T, symmetric operands => B^T==B -------
// 3 phases: (Ahi,Bhi), (Alo,Bhi), (Ahi,Blo); lo*lo dropped (rel ~2^-18).
// MODE 0: write T-enc = 1.5I - 0.5*C   MODE 1: write C-enc   MODE 2: write fp32 C*sqrt(normA)
template <int MODE>
__global__ __launch_bounds__(256) void gemm_bt(const ushort* __restrict__ A,
                                               const ushort* __restrict__ B,
                                               ushort* __restrict__ Cenc,
                                               float* __restrict__ Cout,
                                               const float* __restrict__ norms) {
    __shared__ __attribute__((aligned(16))) ushort As[BM * BKE];  // 16 KB
    __shared__ __attribute__((aligned(16))) ushort Bs[BN * BKE];  // 16 KB

    int b  = blockIdx.y;
    int bm = blockIdx.x >> 2;
    int bn = blockIdx.x & 3;
    size_t matoff = (size_t)b * DIM * KENC;
    const ushort* Ag = A + matoff + (size_t)bm * BM * KENC;
    const ushort* Bg = B + matoff + (size_t)bn * BN * KENC;

    int tid = threadIdx.x;
    int wave = tid >> 6, lane = tid & 63;
    int lane15 = lane & 15, quad = lane >> 4;
    int wrow = (wave >> 1) * 64, wcol = (wave & 1) * 64;

    floatx4 acc[4][4];
    #pragma unroll
    for (int i = 0; i < 4; ++i)
        #pragma unroll
        for (int j = 0; j < 4; ++j)
            acc[i][j] = (floatx4){0.f, 0.f, 0.f, 0.f};

    for (int kt = 0; kt < NKT; ++kt) {
        int ph = kt >> 3;                  // 0: hi*hi, 1: lo*hi, 2: hi*lo
        int kk = (kt & 7) * BKE;
        int kA = kk + (ph == 1 ? 512 : 0);
        int kB = kk + (ph == 2 ? 512 : 0);
        __syncthreads();  // previous tile's LDS reads done before overwrite
        #pragma unroll
        for (int r = 0; r < 4; ++r) {
            int chunk = r * 256 + tid;     // 1024 chunks of 8 bf16 (A tile)
            int row = chunk >> 3;
            int ko = (chunk & 7) << 3;
            gload16(Ag + (size_t)row * KENC + kA + ko, &As[chunk * 8]);
        }
        #pragma unroll
        for (int r = 0; r < 4; ++r) {
            int chunk = r * 256 + tid;
            int row = chunk >> 3;
            int ko = (chunk & 7) << 3;
            gload16(Bg + (size_t)row * KENC + kB + ko, &Bs[chunk * 8]);
        }
        __syncthreads();  // compiler drains vmcnt before s_barrier
        #pragma unroll
        for (int ks = 0; ks < 2; ++ks) {
            int kkf = ks * 32 + quad * 8;
            short8 af[4], bfr[4];
            #pragma unroll
            for (int i = 0; i < 4; ++i)
                af[i] = *(const short8*)&As[(wrow + i * 16 + lane15) * BKE + kkf];
            #pragma unroll
            for (int j = 0; j < 4; ++j)
                bfr[j] = *(const short8*)&Bs[(wcol + j * 16 + lane15) * BKE + kkf];
            #pragma unroll
            for (int i = 0; i < 4; ++i)
                #pragma unroll
                for (int j = 0; j < 4; ++j)
                    acc[i][j] = __builtin_amdgcn_mfma_f32_16x16x32_bf16(af[i], bfr[j], acc[i][j], 0, 0, 0);
        }
    }

    float scale = (MODE == 2) ? sqrtf(norms[b]) : 0.f;
    #pragma unroll
    for (int i = 0; i < 4; ++i) {
        int gr0 = bm * BM + wrow + i * 16 + quad * 4;
        #pragma unroll
        for (int j = 0; j < 4; ++j) {
            int gc = bn * BN + wcol + j * 16 + lane15;
            #pragma unroll
            for (int rr = 0; rr < 4; ++rr) {
                int gr = gr0 + rr;
                float cv = acc[i][j][rr];
                if (MODE == 0) {
                    float tv = (gr == gc ? 1.5f : 0.0f) - 0.5f * cv;
                    ushort hi = f2bf(tv);
                    ushort lo = f2bf(tv - bf2f(hi));
                    Cenc[matoff + (size_t)gr * KENC + gc] = hi;
                    Cenc[matoff + (size_t)gr * KENC + 512 + gc] = lo;
                } else if (MODE == 1) {
                    ushort hi = f2bf(cv);
                    ushort lo = f2bf(cv - bf2f(hi));
                    Cenc[matoff + (size_t)gr * KENC + gc] = hi;
                    Cenc[matoff + (size_t)gr * KENC + 512 + gc] = lo;
                } else {
                    Cout[(size_t)b * DIM * DIM + (size_t)gr * DIM + gc] = cv * scale;
                }
            }
        }
    }
}

extern "C" void kernel_launch(void* const* d_in, const int* in_sizes, int n_in,
                              void* d_out, int out_size, void* d_ws, size_t ws_size,
                              hipStream_t stream) {
    const float* x = (const float*)d_in[0];  // d_in[1] = I, unused
    float* out = (float*)d_out;

    const size_t MATB = (size_t)BATCH * DIM * KENC * sizeof(ushort);  // 64 MB per enc buffer
    char* ws = (char*)d_ws;
    ushort* W0 = (ushort*)(ws + 0 * MATB);
    ushort* W1 = (ushort*)(ws + 1 * MATB);
    ushort* W2 = (ushort*)(ws + 2 * MATB);
    float* norms = (float*)(ws + 3 * MATB);   // ws total: 192 MB + 256 B
    ushort* D = (ushort*)d_out;               // d_out doubles as the 4th encoded buffer

    dim3 gblk(256);
    dim3 ggrid(16, BATCH);

    normA_kernel<<<BATCH, 256, 0, stream>>>(x, norms);
    init_kernel<<<dim3(256, BATCH), 256, 0, stream>>>(x, norms, W0, W1);  // Y0->W0, T1(=Z1)->W1

    // iter 1 (Z=I): Y1 = Y0*T1; Z1 = T1 (aliased, W1)
    gemm_bt<1><<<ggrid, gblk, 0, stream>>>(W0, W1, W2, nullptr, nullptr);  // Y1 -> W2
    // iter 2
    gemm_bt<0><<<ggrid, gblk, 0, stream>>>(W1, W2, W0, nullptr, nullptr);  // T2 = f(Z1*Y1) -> W0
    gemm_bt<1><<<ggrid, gblk, 0, stream>>>(W2, W0, D,  nullptr, nullptr);  // Y2 = Y1*T2 -> D
    gemm_bt<1><<<ggrid, gblk, 0, stream>>>(W0, W1, W2, nullptr, nullptr);  // Z2 = T2*Z1 -> W2
    // iter 3
    gemm_bt<0><<<ggrid, gblk, 0, stream>>>(W2, D,  W0, nullptr, nullptr);  // T3 = f(Z2*Y2) -> W0
    gemm_bt<1><<<ggrid, gblk, 0, stream>>>(D,  W0, W1, nullptr, nullptr);  // Y3 = Y2*T3 -> W1
    gemm_bt<1><<<ggrid, gblk, 0, stream>>>(W0, W2, D,  nullptr, nullptr);  // Z3 = T3*Z2 -> D
    // iter 4
    gemm_bt<0><<<ggrid, gblk, 0, stream>>>(D,  W1, W0, nullptr, nullptr);  // T4 = f(Z3*Y3) -> W0
    gemm_bt<1><<<ggrid, gblk, 0, stream>>>(W1, W0, W2, nullptr, nullptr);  // Y4 = Y3*T4 -> W2
    gemm_bt<1><<<ggrid, gblk, 0, stream>>>(W0, D,  W1, nullptr, nullptr);  // Z4 = T4*Z3 -> W1
    // iter 5 (no Z5 needed)
    gemm_bt<0><<<ggrid, gblk, 0, stream>>>(W1, W2, W0, nullptr, nullptr);  // T5 = f(Z4*Y4) -> W0
    gemm_bt<2><<<ggrid, gblk, 0, stream>>>(W2, W0, nullptr, out, norms);   // out = Y4*T5*sqrt(n) -> D
}

// Round 3
// 1077.952 us; speedup vs baseline: 1.3427x; 1.3427x over previous
//
#include <hip/hip_runtime.h>
#include <hip/hip_bf16.h>
#include <stdint.h>

#define DIM   512
#define BATCH 64
#define KENC  1024          // encoded K layout per row: [hi(512) | lo(512)]
#define BM    128
#define BN    128
#define BKE   64            // K-tile width (bf16 elements)
#define NKT   24            // 3 phases * 8 tiles (K_eff = 1536)

typedef __attribute__((ext_vector_type(8))) short short8;   // 8 bf16 = 4 VGPRs
typedef __attribute__((ext_vector_type(4))) float floatx4;

__device__ __forceinline__ ushort f2bf(float f) {
    __hip_bfloat16 h = __float2bfloat16(f);
    return *(ushort*)&h;
}
__device__ __forceinline__ float bf2f(ushort u) {
    __hip_bfloat16 h = *(__hip_bfloat16*)&u;
    return (float)h;
}

// async global->LDS, 16B per lane. LDS base is wave-uniform; lane i lands at
// base + i*16 -- chunk layout below matches exactly.
typedef __attribute__((address_space(3))) uint32_t lds_u32;
typedef const __attribute__((address_space(1))) uint32_t glb_u32;
__device__ __forceinline__ void gload16(const ushort* g, ushort* l) {
    __builtin_amdgcn_global_load_lds((glb_u32*)g, (lds_u32*)l, 16, 0, 0);
}

// ---------------- kernel 1: partial Frobenius sumsq, 16 partials per matrix ----------------
__global__ __launch_bounds__(256) void norm_partial_kernel(const float* __restrict__ x,
                                                           float* __restrict__ partial) {
    int b = blockIdx.y;          // matrix
    int i = blockIdx.x;          // 16 slices per matrix
    const float4* xv = (const float4*)(x + (size_t)b * DIM * DIM + (size_t)i * (DIM * DIM / 16));
    float s = 0.f;
    #pragma unroll
    for (int r = 0; r < 16; ++r) {             // 256 thr * 16 float4 = 16384 floats
        float4 v = xv[r * 256 + threadIdx.x];
        s += v.x * v.x + v.y * v.y + v.z * v.z + v.w * v.w;
    }
    #pragma unroll
    for (int off = 32; off > 0; off >>= 1) s += __shfl_down(s, off, 64);
    __shared__ float red[4];
    int lane = threadIdx.x & 63, wid = threadIdx.x >> 6;
    if (lane == 0) red[wid] = s;
    __syncthreads();
    if (threadIdx.x == 0) partial[b * 16 + i] = red[0] + red[1] + red[2] + red[3];
}

// -------- kernel 2: finish norm; encode Y0 = x/normA ; T1 = 1.5I - 0.5*Y0 (Z1 aliases T1) --------
__global__ __launch_bounds__(256) void init_kernel(const float* __restrict__ x,
                                                   const float* __restrict__ partial,
                                                   float* __restrict__ norms,
                                                   ushort* __restrict__ Yenc,
                                                   ushort* __restrict__ Tenc) {
    int b = blockIdx.y;
    float s = 0.f;
    #pragma unroll
    for (int p = 0; p < 16; ++p) s += partial[b * 16 + p];
    float nrm = sqrtf(s);
    if (blockIdx.x == 0 && threadIdx.x == 0) norms[b] = nrm;
    float inv = 1.0f / nrm;
    int idx = (blockIdx.x * 256 + threadIdx.x) * 4;  // element index in matrix
    int r = idx >> 9;
    int c = idx & 511;
    float4 v = *(const float4*)(x + (size_t)b * DIM * DIM + idx);
    float yv[4] = {v.x * inv, v.y * inv, v.z * inv, v.w * inv};
    size_t base = (size_t)b * DIM * KENC + (size_t)r * KENC;
    ushort yhi[4], ylo[4], thi[4], tlo[4];
    #pragma unroll
    for (int j = 0; j < 4; ++j) {
        float y = yv[j];
        yhi[j] = f2bf(y);
        ylo[j] = f2bf(y - bf2f(yhi[j]));
        float t = ((c + j) == r ? 1.5f : 0.0f) - 0.5f * y;
        thi[j] = f2bf(t);
        tlo[j] = f2bf(t - bf2f(thi[j]));
    }
    *(ushort4*)(Yenc + base + c)       = *(ushort4*)yhi;
    *(ushort4*)(Yenc + base + 512 + c) = *(ushort4*)ylo;
    *(ushort4*)(Tenc + base + c)       = *(ushort4*)thi;
    *(ushort4*)(Tenc + base + 512 + c) = *(ushort4*)tlo;
}

// ------- batched split-bf16 NT-GEMM: C = (Ahi+Alo)*(Bhi+Blo)^T, symmetric operands => B^T==B -------
// 3 phases: (Ahi,Bhi), (Alo,Bhi), (Ahi,Blo); lo*lo dropped (rel ~2^-18).
// MODE 0: write T-enc = 1.5I - 0.5*C   MODE 1: write C-enc   MODE 2: write fp32 C*sqrt(normA)
// Block swizzle: all 16 tiles of a matrix on one XCD (assumes flat%8 round-robin placement)
// so the ~4 MB per-matrix operand set is served from that XCD's L2, not L3.
template <int MODE>
__global__ __launch_bounds__(256) void gemm_bt(const ushort* __restrict__ A,
                                               const ushort* __restrict__ B,
                                               ushort* __restrict__ Cenc,
                                               float* __restrict__ Cout,
                                               const float* __restrict__ norms) {
    __shared__ __attribute__((aligned(16))) ushort As[BM * BKE];  // 16 KB
    __shared__ __attribute__((aligned(16))) ushort Bs[BN * BKE];  // 16 KB

    int f = blockIdx.x;
    int xcd = f & 7;             // assumed XCD of this block (round-robin)
    int g   = f >> 3;            // 0..127 within XCD
    int b   = xcd + 8 * (g >> 4);// 8 matrices per XCD, tiles contiguous in time
    int t   = g & 15;
    int bm  = t >> 2;
    int bn  = t & 3;

    size_t matoff = (size_t)b * DIM * KENC;
    const ushort* Ag = A + matoff + (size_t)bm * BM * KENC;
    const ushort* Bg = B + matoff + (size_t)bn * BN * KENC;

    int tid = threadIdx.x;
    int wave = tid >> 6, lane = tid & 63;
    int lane15 = lane & 15, quad = lane >> 4;
    int wrow = (wave >> 1) * 64, wcol = (wave & 1) * 64;

    floatx4 acc[4][4];
    #pragma unroll
    for (int i = 0; i < 4; ++i)
        #pragma unroll
        for (int j = 0; j < 4; ++j)
            acc[i][j] = (floatx4){0.f, 0.f, 0.f, 0.f};

    for (int kt = 0; kt < NKT; ++kt) {
        int ph = kt >> 3;                  // 0: hi*hi, 1: lo*hi, 2: hi*lo
        int kk = (kt & 7) * BKE;
        int kA = kk + (ph == 1 ? 512 : 0);
        int kB = kk + (ph == 2 ? 512 : 0);
        __syncthreads();  // previous tile's LDS reads done before overwrite
        #pragma unroll
        for (int r = 0; r < 4; ++r) {
            int chunk = r * 256 + tid;     // 1024 chunks of 8 bf16 (A tile)
            int row = chunk >> 3;
            int ko = (chunk & 7) << 3;
            gload16(Ag + (size_t)row * KENC + kA + ko, &As[chunk * 8]);
        }
        #pragma unroll
        for (int r = 0; r < 4; ++r) {
            int chunk = r * 256 + tid;
            int row = chunk >> 3;
            int ko = (chunk & 7) << 3;
            gload16(Bg + (size_t)row * KENC + kB + ko, &Bs[chunk * 8]);
        }
        __syncthreads();  // compiler drains vmcnt before s_barrier
        #pragma unroll
        for (int ks = 0; ks < 2; ++ks) {
            int kkf = ks * 32 + quad * 8;
            short8 af[4], bfr[4];
            #pragma unroll
            for (int i = 0; i < 4; ++i)
                af[i] = *(const short8*)&As[(wrow + i * 16 + lane15) * BKE + kkf];
            #pragma unroll
            for (int j = 0; j < 4; ++j)
                bfr[j] = *(const short8*)&Bs[(wcol + j * 16 + lane15) * BKE + kkf];
            #pragma unroll
            for (int i = 0; i < 4; ++i)
                #pragma unroll
                for (int j = 0; j < 4; ++j)
                    acc[i][j] = __builtin_amdgcn_mfma_f32_16x16x32_bf16(af[i], bfr[j], acc[i][j], 0, 0, 0);
        }
    }

    float scale = (MODE == 2) ? sqrtf(norms[b]) : 0.f;
    #pragma unroll
    for (int i = 0; i < 4; ++i) {
        int gr0 = bm * BM + wrow + i * 16 + quad * 4;
        #pragma unroll
        for (int j = 0; j < 4; ++j) {
            int gc = bn * BN + wcol + j * 16 + lane15;
            #pragma unroll
            for (int rr = 0; rr < 4; ++rr) {
                int gr = gr0 + rr;
                float cv = acc[i][j][rr];
                if (MODE == 0) {
                    float tv = (gr == gc ? 1.5f : 0.0f) - 0.5f * cv;
                    ushort hi = f2bf(tv);
                    ushort lo = f2bf(tv - bf2f(hi));
                    Cenc[matoff + (size_t)gr * KENC + gc] = hi;
                    Cenc[matoff + (size_t)gr * KENC + 512 + gc] = lo;
                } else if (MODE == 1) {
                    ushort hi = f2bf(cv);
                    ushort lo = f2bf(cv - bf2f(hi));
                    Cenc[matoff + (size_t)gr * KENC + gc] = hi;
                    Cenc[matoff + (size_t)gr * KENC + 512 + gc] = lo;
                } else {
                    Cout[(size_t)b * DIM * DIM + (size_t)gr * DIM + gc] = cv * scale;
                }
            }
        }
    }
}

extern "C" void kernel_launch(void* const* d_in, const int* in_sizes, int n_in,
                              void* d_out, int out_size, void* d_ws, size_t ws_size,
                              hipStream_t stream) {
    const float* x = (const float*)d_in[0];  // d_in[1] = I, unused
    float* out = (float*)d_out;

    const size_t MATB = (size_t)BATCH * DIM * KENC * sizeof(ushort);  // 64 MB per enc buffer
    char* ws = (char*)d_ws;
    ushort* W0 = (ushort*)(ws + 0 * MATB);
    ushort* W1 = (ushort*)(ws + 1 * MATB);
    ushort* W2 = (ushort*)(ws + 2 * MATB);
    float* partial = (float*)(ws + 3 * MATB);          // 64*16 floats
    float* norms   = (float*)(ws + 3 * MATB + 4096);   // 64 floats
    ushort* D = (ushort*)d_out;               // d_out doubles as the 4th encoded buffer

    dim3 gblk(256);
    dim3 ggrid(1024);  // flat, swizzled inside

    norm_partial_kernel<<<dim3(16, BATCH), 256, 0, stream>>>(x, partial);
    init_kernel<<<dim3(256, BATCH), 256, 0, stream>>>(x, partial, norms, W0, W1);  // Y0->W0, T1(=Z1)->W1

    // iter 1 (Z=I): Y1 = Y0*T1; Z1 = T1 (aliased, W1)
    gemm_bt<1><<<ggrid, gblk, 0, stream>>>(W0, W1, W2, nullptr, nullptr);  // Y1 -> W2
    // iter 2
    gemm_bt<0><<<ggrid, gblk, 0, stream>>>(W1, W2, W0, nullptr, nullptr);  // T2 = f(Z1*Y1) -> W0
    gemm_bt<1><<<ggrid, gblk, 0, stream>>>(W2, W0, D,  nullptr, nullptr);  // Y2 = Y1*T2 -> D
    gemm_bt<1><<<ggrid, gblk, 0, stream>>>(W0, W1, W2, nullptr, nullptr);  // Z2 = T2*Z1 -> W2
    // iter 3
    gemm_bt<0><<<ggrid, gblk, 0, stream>>>(W2, D,  W0, nullptr, nullptr);  // T3 = f(Z2*Y2) -> W0
    gemm_bt<1><<<ggrid, gblk, 0, stream>>>(D,  W0, W1, nullptr, nullptr);  // Y3 = Y2*T3 -> W1
    gemm_bt<1><<<ggrid, gblk, 0, stream>>>(W0, W2, D,  nullptr, nullptr);  // Z3 = T3*Z2 -> D
    // iter 4
    gemm_bt<0><<<ggrid, gblk, 0, stream>>>(D,  W1, W0, nullptr, nullptr);  // T4 = f(Z3*Y3) -> W0
    gemm_bt<1><<<ggrid, gblk, 0, stream>>>(W1, W0, W2, nullptr, nullptr);  // Y4 = Y3*T4 -> W2
    gemm_bt<1><<<ggrid, gblk, 0, stream>>>(W0, D,  W1, nullptr, nullptr);  // Z4 = T4*Z3 -> W1
    // iter 5 (no Z5 needed)
    gemm_bt<0><<<ggrid, gblk, 0, stream>>>(W1, W2, W0, nullptr, nullptr);  // T5 = f(Z4*Y4) -> W0
    gemm_bt<2><<<ggrid, gblk, 0, stream>>>(W2, W0, nullptr, out, norms);   // out = Y4*T5*sqrt(n) -> D
}

// Round 4
// 967.900 us; speedup vs baseline: 1.4954x; 1.1137x over previous
//
#include <hip/hip_runtime.h>
#include <hip/hip_bf16.h>
#include <stdint.h>

#define DIM   512
#define BATCH 64
#define KENC  1024          // encoded K layout per row: [hi(512) | lo(512)]
#define BM    128
#define BN    128
#define BKE   64            // K-tile width (bf16 elements)
#define NKT   24            // 3 phases * 8 tiles (K_eff = 1536)

typedef __attribute__((ext_vector_type(8))) short short8;   // 8 bf16 = 4 VGPRs
typedef __attribute__((ext_vector_type(4))) float floatx4;

__device__ __forceinline__ ushort f2bf(float f) {
    __hip_bfloat16 h = __float2bfloat16(f);
    return *(ushort*)&h;
}
__device__ __forceinline__ float bf2f(ushort u) {
    __hip_bfloat16 h = *(__hip_bfloat16*)&u;
    return (float)h;
}

// async global->LDS, 16B per lane. LDS base is wave-uniform; lane i lands at
// base + i*16 -- chunk layout below matches exactly.
typedef __attribute__((address_space(3))) uint32_t lds_u32;
typedef const __attribute__((address_space(1))) uint32_t glb_u32;
__device__ __forceinline__ void gload16(const ushort* g, ushort* l) {
    __builtin_amdgcn_global_load_lds((glb_u32*)g, (lds_u32*)l, 16, 0, 0);
}

// ---------------- kernel 1: partial Frobenius sumsq, 16 partials per matrix ----------------
__global__ __launch_bounds__(256) void norm_partial_kernel(const float* __restrict__ x,
                                                           float* __restrict__ partial) {
    int b = blockIdx.y;          // matrix
    int i = blockIdx.x;          // 16 slices per matrix
    const float4* xv = (const float4*)(x + (size_t)b * DIM * DIM + (size_t)i * (DIM * DIM / 16));
    float s = 0.f;
    #pragma unroll
    for (int r = 0; r < 16; ++r) {             // 256 thr * 16 float4 = 16384 floats
        float4 v = xv[r * 256 + threadIdx.x];
        s += v.x * v.x + v.y * v.y + v.z * v.z + v.w * v.w;
    }
    #pragma unroll
    for (int off = 32; off > 0; off >>= 1) s += __shfl_down(s, off, 64);
    __shared__ float red[4];
    int lane = threadIdx.x & 63, wid = threadIdx.x >> 6;
    if (lane == 0) red[wid] = s;
    __syncthreads();
    if (threadIdx.x == 0) partial[b * 16 + i] = red[0] + red[1] + red[2] + red[3];
}

// -------- kernel 2: finish norm; encode Y0 = x/normA ; T1 = 1.5I - 0.5*Y0 (Z1 aliases T1) --------
__global__ __launch_bounds__(256) void init_kernel(const float* __restrict__ x,
                                                   const float* __restrict__ partial,
                                                   float* __restrict__ norms,
                                                   ushort* __restrict__ Yenc,
                                                   ushort* __restrict__ Tenc) {
    int b = blockIdx.y;
    float s = 0.f;
    #pragma unroll
    for (int p = 0; p < 16; ++p) s += partial[b * 16 + p];
    float nrm = sqrtf(s);
    if (blockIdx.x == 0 && threadIdx.x == 0) norms[b] = nrm;
    float inv = 1.0f / nrm;
    int idx = (blockIdx.x * 256 + threadIdx.x) * 4;  // element index in matrix
    int r = idx >> 9;
    int c = idx & 511;
    float4 v = *(const float4*)(x + (size_t)b * DIM * DIM + idx);
    float yv[4] = {v.x * inv, v.y * inv, v.z * inv, v.w * inv};
    size_t base = (size_t)b * DIM * KENC + (size_t)r * KENC;
    ushort yhi[4], ylo[4], thi[4], tlo[4];
    #pragma unroll
    for (int j = 0; j < 4; ++j) {
        float y = yv[j];
        yhi[j] = f2bf(y);
        ylo[j] = f2bf(y - bf2f(yhi[j]));
        float t = ((c + j) == r ? 1.5f : 0.0f) - 0.5f * y;
        thi[j] = f2bf(t);
        tlo[j] = f2bf(t - bf2f(thi[j]));
    }
    *(ushort4*)(Yenc + base + c)       = *(ushort4*)yhi;
    *(ushort4*)(Yenc + base + 512 + c) = *(ushort4*)ylo;
    *(ushort4*)(Tenc + base + c)       = *(ushort4*)thi;
    *(ushort4*)(Tenc + base + 512 + c) = *(ushort4*)tlo;
}

// ------- batched split-bf16 NT-GEMM: C = (Ahi+Alo)*(Bhi+Blo)^T, symmetric operands => B^T==B -------
// 3 phases: (Ahi,Bhi), (Alo,Bhi), (Ahi,Blo); lo*lo dropped (rel ~2^-18).
// LDS bank-conflict fix: XOR swizzle. Logical 8-elem chunk kc of row r lives at
// physical chunk (kc ^ (r&7)). global_load_lds LDS dests are unchanged (lane-order
// contiguous); we permute the per-lane GLOBAL source instead. Fragment reads then
// spread 16 lanes across 8 bank groups (2-way alias = free) instead of 16-way.
// MODE 0: write T-enc = 1.5I - 0.5*C   MODE 1: write C-enc   MODE 2: write fp32 C*sqrt(normA)
template <int MODE>
__global__ __launch_bounds__(256) void gemm_bt(const ushort* __restrict__ A,
                                               const ushort* __restrict__ B,
                                               ushort* __restrict__ Cenc,
                                               float* __restrict__ Cout,
                                               const float* __restrict__ norms) {
    __shared__ __attribute__((aligned(16))) ushort As[BM * BKE];  // 16 KB
    __shared__ __attribute__((aligned(16))) ushort Bs[BN * BKE];  // 16 KB

    int f = blockIdx.x;
    int xcd = f & 7;             // assumed XCD of this block (round-robin)
    int g   = f >> 3;            // 0..127 within XCD
    int b   = xcd + 8 * (g >> 4);// 8 matrices per XCD
    int t   = g & 15;
    int bm  = t >> 2;
    int bn  = t & 3;

    size_t matoff = (size_t)b * DIM * KENC;
    const ushort* Ag = A + matoff + (size_t)bm * BM * KENC;
    const ushort* Bg = B + matoff + (size_t)bn * BN * KENC;

    int tid = threadIdx.x;
    int wave = tid >> 6, lane = tid & 63;
    int lane15 = lane & 15, quad = lane >> 4;
    int wrow = (wave >> 1) * 64, wcol = (wave & 1) * 64;
    int swz7 = lane15 & 7;       // row&7 for all fragment rows this lane touches

    floatx4 acc[4][4];
    #pragma unroll
    for (int i = 0; i < 4; ++i)
        #pragma unroll
        for (int j = 0; j < 4; ++j)
            acc[i][j] = (floatx4){0.f, 0.f, 0.f, 0.f};

    for (int kt = 0; kt < NKT; ++kt) {
        int ph = kt >> 3;                  // 0: hi*hi, 1: lo*hi, 2: hi*lo
        int kk = (kt & 7) * BKE;
        int kA = kk + (ph == 1 ? 512 : 0);
        int kB = kk + (ph == 2 ? 512 : 0);
        __syncthreads();  // previous tile's LDS reads done before overwrite
        #pragma unroll
        for (int r = 0; r < 4; ++r) {
            int chunk = r * 256 + tid;     // 1024 chunks of 8 bf16 (A tile)
            int row = chunk >> 3;
            int ko = ((chunk & 7) ^ (row & 7)) << 3;   // XOR swizzle on global source
            gload16(Ag + (size_t)row * KENC + kA + ko, &As[chunk * 8]);
        }
        #pragma unroll
        for (int r = 0; r < 4; ++r) {
            int chunk = r * 256 + tid;
            int row = chunk >> 3;
            int ko = ((chunk & 7) ^ (row & 7)) << 3;
            gload16(Bg + (size_t)row * KENC + kB + ko, &Bs[chunk * 8]);
        }
        __syncthreads();  // compiler drains vmcnt before s_barrier
        #pragma unroll
        for (int ks = 0; ks < 2; ++ks) {
            int kcL = ks * 4 + quad;               // logical chunk 0..7
            int swz = (kcL ^ swz7) << 3;           // physical element offset in row
            short8 af[4], bfr[4];
            #pragma unroll
            for (int i = 0; i < 4; ++i)
                af[i] = *(const short8*)&As[(wrow + i * 16 + lane15) * BKE + swz];
            #pragma unroll
            for (int j = 0; j < 4; ++j)
                bfr[j] = *(const short8*)&Bs[(wcol + j * 16 + lane15) * BKE + swz];
            #pragma unroll
            for (int i = 0; i < 4; ++i)
                #pragma unroll
                for (int j = 0; j < 4; ++j)
                    acc[i][j] = __builtin_amdgcn_mfma_f32_16x16x32_bf16(af[i], bfr[j], acc[i][j], 0, 0, 0);
        }
    }

    float scale = (MODE == 2) ? sqrtf(norms[b]) : 0.f;
    #pragma unroll
    for (int i = 0; i < 4; ++i) {
        int gr0 = bm * BM + wrow + i * 16 + quad * 4;
        #pragma unroll
        for (int j = 0; j < 4; ++j) {
            int gc = bn * BN + wcol + j * 16 + lane15;
            #pragma unroll
            for (int rr = 0; rr < 4; ++rr) {
                int gr = gr0 + rr;
                float cv = acc[i][j][rr];
                if (MODE == 0) {
                    float tv = (gr == gc ? 1.5f : 0.0f) - 0.5f * cv;
                    ushort hi = f2bf(tv);
                    ushort lo = f2bf(tv - bf2f(hi));
                    Cenc[matoff + (size_t)gr * KENC + gc] = hi;
                    Cenc[matoff + (size_t)gr * KENC + 512 + gc] = lo;
                } else if (MODE == 1) {
                    ushort hi = f2bf(cv);
                    ushort lo = f2bf(cv - bf2f(hi));
                    Cenc[matoff + (size_t)gr * KENC + gc] = hi;
                    Cenc[matoff + (size_t)gr * KENC + 512 + gc] = lo;
                } else {
                    Cout[(size_t)b * DIM * DIM + (size_t)gr * DIM + gc] = cv * scale;
                }
            }
        }
    }
}

extern "C" void kernel_launch(void* const* d_in, const int* in_sizes, int n_in,
                              void* d_out, int out_size, void* d_ws, size_t ws_size,
                              hipStream_t stream) {
    const float* x = (const float*)d_in[0];  // d_in[1] = I, unused
    float* out = (float*)d_out;

    const size_t MATB = (size_t)BATCH * DIM * KENC * sizeof(ushort);  // 64 MB per enc buffer
    char* ws = (char*)d_ws;
    ushort* W0 = (ushort*)(ws + 0 * MATB);
    ushort* W1 = (ushort*)(ws + 1 * MATB);
    ushort* W2 = (ushort*)(ws + 2 * MATB);
    float* partial = (float*)(ws + 3 * MATB);          // 64*16 floats
    float* norms   = (float*)(ws + 3 * MATB + 4096);   // 64 floats
    ushort* D = (ushort*)d_out;               // d_out doubles as the 4th encoded buffer

    dim3 gblk(256);
    dim3 ggrid(1024);  // flat, swizzled inside

    norm_partial_kernel<<<dim3(16, BATCH), 256, 0, stream>>>(x, partial);
    init_kernel<<<dim3(256, BATCH), 256, 0, stream>>>(x, partial, norms, W0, W1);  // Y0->W0, T1(=Z1)->W1

    // iter 1 (Z=I): Y1 = Y0*T1; Z1 = T1 (aliased, W1)
    gemm_bt<1><<<ggrid, gblk, 0, stream>>>(W0, W1, W2, nullptr, nullptr);  // Y1 -> W2
    // iter 2
    gemm_bt<0><<<ggrid, gblk, 0, stream>>>(W1, W2, W0, nullptr, nullptr);  // T2 = f(Z1*Y1) -> W0
    gemm_bt<1><<<ggrid, gblk, 0, stream>>>(W2, W0, D,  nullptr, nullptr);  // Y2 = Y1*T2 -> D
    gemm_bt<1><<<ggrid, gblk, 0, stream>>>(W0, W1, W2, nullptr, nullptr);  // Z2 = T2*Z1 -> W2
    // iter 3
    gemm_bt<0><<<ggrid, gblk, 0, stream>>>(W2, D,  W0, nullptr, nullptr);  // T3 = f(Z2*Y2) -> W0
    gemm_bt<1><<<ggrid, gblk, 0, stream>>>(D,  W0, W1, nullptr, nullptr);  // Y3 = Y2*T3 -> W1
    gemm_bt<1><<<ggrid, gblk, 0, stream>>>(W0, W2, D,  nullptr, nullptr);  // Z3 = T3*Z2 -> D
    // iter 4
    gemm_bt<0><<<ggrid, gblk, 0, stream>>>(D,  W1, W0, nullptr, nullptr);  // T4 = f(Z3*Y3) -> W0
    gemm_bt<1><<<ggrid, gblk, 0, stream>>>(W1, W0, W2, nullptr, nullptr);  // Y4 = Y3*T4 -> W2
    gemm_bt<1><<<ggrid, gblk, 0, stream>>>(W0, D,  W1, nullptr, nullptr);  // Z4 = T4*Z3 -> W1
    // iter 5 (no Z5 needed)
    gemm_bt<0><<<ggrid, gblk, 0, stream>>>(W1, W2, W0, nullptr, nullptr);  // T5 = f(Z4*Y4) -> W0
    gemm_bt<2><<<ggrid, gblk, 0, stream>>>(W2, W0, nullptr, out, norms);   // out = Y4*T5*sqrt(n) -> D
}

// Round 5
// 854.147 us; speedup vs baseline: 1.6945x; 1.1332x over previous
//
#include <hip/hip_runtime.h>
#include <hip/hip_bf16.h>
#include <stdint.h>

#define DIM   512
#define BATCH 64
#define KENC  1024
#define BM    128
#define BN    128
#define BKT   32
#define NKT   16

typedef __attribute__((ext_vector_type(8))) short short8;
typedef __attribute__((ext_vector_type(4))) float floatx4;

__device__ __forceinline__ ushort f2bf(float f) {
    __hip_bfloat16 h = __float2bfloat16(f);
    return *(ushort*)&h;
}
__device__ __forceinline__ float bf2f(ushort u) {
    __hip_bfloat16 h = *(__hip_bfloat16*)&u;
    return (float)h;
}

typedef __attribute__((address_space(3))) uint32_t lds_u32;
typedef const __attribute__((address_space(1))) uint32_t glb_u32;
__device__ __forceinline__ void gload16(const ushort* g, ushort* l) {
    __builtin_amdgcn_global_load_lds((glb_u32*)g, (lds_u32*)l, 16, 0, 0);
}

__global__ __launch_bounds__(256) void norm_partial_kernel(const float* __restrict__ x,
                                                           float* __restrict__ partial) {
    int b = blockIdx.y;
    int i = blockIdx.x;
    const float4* xv = (const float4*)(x + (size_t)b * DIM * DIM + (size_t)i * (DIM * DIM / 16));
    float s = 0.f;
    #pragma unroll
    for (int r = 0; r < 16; ++r) {
        float4 v = xv[r * 256 + threadIdx.x];
        s += v.x * v.x + v.y * v.y + v.z * v.z + v.w * v.w;
    }
    #pragma unroll
    for (int off = 32; off > 0; off >>= 1) s += __shfl_down(s, off, 64);
    __shared__ float red[4];
    int lane = threadIdx.x & 63, wid = threadIdx.x >> 6;
    if (lane == 0) red[wid] = s;
    __syncthreads();
    if (threadIdx.x == 0) partial[b * 16 + i] = red[0] + red[1] + red[2] + red[3];
}

__global__ __launch_bounds__(256) void init_kernel(const float* __restrict__ x,
                                                   const float* __restrict__ partial,
                                                   float* __restrict__ norms,
                                                   ushort* __restrict__ Yenc,
                                                   ushort* __restrict__ Tenc) {
    int b = blockIdx.y;
    float s = 0.f;
    #pragma unroll
    for (int p = 0; p < 16; ++p) s += partial[b * 16 + p];
    float nrm = sqrtf(s);
    if (blockIdx.x == 0 && threadIdx.x == 0) norms[b] = nrm;
    float inv = 1.0f / nrm;
    int idx = (blockIdx.x * 256 + threadIdx.x) * 4;
    int r = idx >> 9;
    int c = idx & 511;
    float4 v = *(const float4*)(x + (size_t)b * DIM * DIM + idx);
    float yv[4] = {v.x * inv, v.y * inv, v.z * inv, v.w * inv};
    size_t base = (size_t)b * DIM * KENC + (size_t)r * KENC;
    ushort yhi[4], ylo[4], thi[4], tlo[4];
    #pragma unroll
    for (int j = 0; j < 4; ++j) {
        float y = yv[j];
        yhi[j] = f2bf(y);
        ylo[j] = f2bf(y - bf2f(yhi[j]));
        float t = ((c + j) == r ? 1.5f : 0.0f) - 0.5f * y;
        thi[j] = f2bf(t);
        tlo[j] = f2bf(t - bf2f(thi[j]));
    }
    *(ushort4*)(Yenc + base + c)       = *(ushort4*)yhi;
    *(ushort4*)(Yenc + base + 512 + c) = *(ushort4*)ylo;
    *(ushort4*)(Tenc + base + c)       = *(ushort4*)thi;
    *(ushort4*)(Tenc + base + 512 + c) = *(ushort4*)tlo;
}

// 4-plane staging (Ahi,Alo,Bhi,Blo; 8 KB each), 3 phase-products per K-tile.
// XOR swizzle: physical chunk pc of row r holds logical chunk pc ^ ((r>>1)&3)
// => fragment ds_read_b128 is 2-way bank-aliased (free, m136).
__device__ __forceinline__ void gemm_core(const ushort* Ag, const ushort* Bg,
                                          ushort* sm, floatx4 (&acc)[4][4], int tid) {
    ushort* Ash = sm;
    ushort* Asl = sm + 4096;
    ushort* Bsh = sm + 8192;
    ushort* Bsl = sm + 12288;
    int lane = tid & 63;
    int lane15 = lane & 15, quad = lane >> 4;
    int wave = tid >> 6;
    int wrow = (wave >> 1) * 64, wcol = (wave & 1) * 64;
    int s2 = (lane15 >> 1) & 3;
    int fo = ((quad ^ s2) << 3);

    for (int kt = 0; kt < NKT; ++kt) {
        int k0 = kt * BKT;
        __syncthreads();
        #pragma unroll
        for (int r = 0; r < 2; ++r) {
            int c = r * 256 + tid;
            int row = c >> 2;
            int kc = (((c & 3) ^ ((row >> 1) & 3)) << 3);
            const ushort* ar = Ag + (size_t)row * KENC + k0 + kc;
            const ushort* br = Bg + (size_t)row * KENC + k0 + kc;
            gload16(ar,       &Ash[c * 8]);
            gload16(ar + 512, &Asl[c * 8]);
            gload16(br,       &Bsh[c * 8]);
            gload16(br + 512, &Bsl[c * 8]);
        }
        __syncthreads();
        short8 ah[4], bh[4], xl[4];
        #pragma unroll
        for (int i = 0; i < 4; ++i)
            ah[i] = *(const short8*)&Ash[(wrow + i * 16 + lane15) * BKT + fo];
        #pragma unroll
        for (int j = 0; j < 4; ++j)
            bh[j] = *(const short8*)&Bsh[(wcol + j * 16 + lane15) * BKT + fo];
        #pragma unroll
        for (int i = 0; i < 4; ++i)
            #pragma unroll
            for (int j = 0; j < 4; ++j)
                acc[i][j] = __builtin_amdgcn_mfma_f32_16x16x32_bf16(ah[i], bh[j], acc[i][j], 0, 0, 0);
        #pragma unroll
        for (int j = 0; j < 4; ++j)
            xl[j] = *(const short8*)&Bsl[(wcol + j * 16 + lane15) * BKT + fo];
        #pragma unroll
        for (int i = 0; i < 4; ++i)
            #pragma unroll
            for (int j = 0; j < 4; ++j)
                acc[i][j] = __builtin_amdgcn_mfma_f32_16x16x32_bf16(ah[i], xl[j], acc[i][j], 0, 0, 0);
        #pragma unroll
        for (int i = 0; i < 4; ++i)
            xl[i] = *(const short8*)&Asl[(wrow + i * 16 + lane15) * BKT + fo];
        #pragma unroll
        for (int i = 0; i < 4; ++i)
            #pragma unroll
            for (int j = 0; j < 4; ++j)
                acc[i][j] = __builtin_amdgcn_mfma_f32_16x16x32_bf16(xl[i], bh[j], acc[i][j], 0, 0, 0);
    }
}

__device__ __forceinline__ void store_enc(ushort* Cenc, size_t matoff, int gr, int gc, float v) {
    ushort hi = f2bf(v);
    ushort lo = f2bf(v - bf2f(hi));
    Cenc[matoff + (size_t)gr * KENC + gc] = hi;
    Cenc[matoff + (size_t)gr * KENC + 512 + gc] = lo;
}

// MODE 0: T-enc = 1.5I - 0.5*C   MODE 1: C-enc   MODE 2: fp32 C*sqrt(normA)
template <int MODE>
__global__ __launch_bounds__(256) void gemm_bt(const ushort* __restrict__ A,
                                               const ushort* __restrict__ B,
                                               ushort* __restrict__ Cenc,
                                               float* __restrict__ Cout,
                                               const float* __restrict__ norms) {
    __shared__ __attribute__((aligned(16))) ushort sm[4 * 4096];

    int f = blockIdx.x;
    int xcd = f & 7;
    int g   = f >> 3;
    int b   = xcd + 8 * (g >> 4);
    int t   = g & 15;
    int bm  = t >> 2;
    int bn  = t & 3;

    size_t matoff = (size_t)b * DIM * KENC;
    const ushort* Ag = A + matoff + (size_t)bm * BM * KENC;
    const ushort* Bg = B + matoff + (size_t)bn * BN * KENC;

    int tid = threadIdx.x;
    floatx4 acc[4][4];
    #pragma unroll
    for (int i = 0; i < 4; ++i)
        #pragma unroll
        for (int j = 0; j < 4; ++j)
            acc[i][j] = (floatx4){0.f, 0.f, 0.f, 0.f};

    gemm_core(Ag, Bg, sm, acc, tid);

    int lane = tid & 63;
    int lane15 = lane & 15, quad = lane >> 4;
    int wave = tid >> 6;
    int wrow = (wave >> 1) * 64, wcol = (wave & 1) * 64;
    float scale = (MODE == 2) ? sqrtf(norms[b]) : 0.f;
    #pragma unroll
    for (int i = 0; i < 4; ++i) {
        int gr0 = bm * BM + wrow + i * 16 + quad * 4;
        #pragma unroll
        for (int j = 0; j < 4; ++j) {
            int gc = bn * BN + wcol + j * 16 + lane15;
            #pragma unroll
            for (int rr = 0; rr < 4; ++rr) {
                int gr = gr0 + rr;
                float cv = acc[i][j][rr];
                if (MODE == 0) {
                    store_enc(Cenc, matoff, gr, gc, (gr == gc ? 1.5f : 0.0f) - 0.5f * cv);
                } else if (MODE == 1) {
                    store_enc(Cenc, matoff, gr, gc, cv);
                } else {
                    Cout[(size_t)b * DIM * DIM + (size_t)gr * DIM + gc] = cv * scale;
                }
            }
        }
    }
}

// merged dispatch: even blocks Y' = Y*T, odd blocks Z' = T*Z (2048 blocks)
__global__ __launch_bounds__(256) void gemm_yz(const ushort* __restrict__ Y,
                                               const ushort* __restrict__ T,
                                               ushort* __restrict__ Yn,
                                               const ushort* __restrict__ Z,
                                               ushort* __restrict__ Zn) {
    __shared__ __attribute__((aligned(16))) ushort sm[4 * 4096];

    int f0 = blockIdx.x;
    int sel = f0 & 1;
    int f = f0 >> 1;
    int xcd = f & 7;
    int g   = f >> 3;
    int b   = xcd + 8 * (g >> 4);
    int t   = g & 15;
    int bm  = t >> 2;
    int bn  = t & 3;

    size_t matoff = (size_t)b * DIM * KENC;
    const ushort* Abase = sel ? T : Y;
    const ushort* Bbase = sel ? Z : T;
    ushort* Cenc = sel ? Zn : Yn;
    const ushort* Ag = Abase + matoff + (size_t)bm * BM * KENC;
    const ushort* Bg = Bbase + matoff + (size_t)bn * BN * KENC;

    int tid = threadIdx.x;
    floatx4 acc[4][4];
    #pragma unroll
    for (int i = 0; i < 4; ++i)
        #pragma unroll
        for (int j = 0; j < 4; ++j)
            acc[i][j] = (floatx4){0.f, 0.f, 0.f, 0.f};

    gemm_core(Ag, Bg, sm, acc, tid);

    int lane = tid & 63;
    int lane15 = lane & 15, quad = lane >> 4;
    int wave = tid >> 6;
    int wrow = (wave >> 1) * 64, wcol = (wave & 1) * 64;
    #pragma unroll
    for (int i = 0; i < 4; ++i) {
        int gr0 = bm * BM + wrow + i * 16 + quad * 4;
        #pragma unroll
        for (int j = 0; j < 4; ++j) {
            int gc = bn * BN + wcol + j * 16 + lane15;
            #pragma unroll
            for (int rr = 0; rr < 4; ++rr)
                store_enc(Cenc, matoff, gr0 + rr, gc, acc[i][j][rr]);
        }
    }
}

extern "C" void kernel_launch(void* const* d_in, const int* in_sizes, int n_in,
                              void* d_out, int out_size, void* d_ws, size_t ws_size,
                              hipStream_t stream) {
    const float* x = (const float*)d_in[0];  // d_in[1] = I, unused
    float* out = (float*)d_out;

    const size_t MATB = (size_t)BATCH * DIM * KENC * sizeof(ushort);  // 64 MB
    char* ws = (char*)d_ws;
    ushort* W0 = (ushort*)(ws + 0 * MATB);
    ushort* W1 = (ushort*)(ws + 1 * MATB);
    ushort* W2 = (ushort*)(ws + 2 * MATB);
    float* partial = (float*)(ws + 3 * MATB);          // 192 MB + 4 KB (same footprint as R4)
    float* norms   = (float*)(ws + 3 * MATB + 4096);
    ushort* D = (ushort*)d_out;  // encoded scratch slot #4; final fp32 GEMM overwrites last

    dim3 gblk(256);
    dim3 g1(1024);
    dim3 g2(2048);

    norm_partial_kernel<<<dim3(16, BATCH), 256, 0, stream>>>(x, partial);
    init_kernel<<<dim3(256, BATCH), 256, 0, stream>>>(x, partial, norms, W0, W1);  // Y0->W0, T1(=Z1)->W1

    // iter 1: Y1 = Y0*T1 -> W2 ; Z1 = T1 (W1).             live: Y1=W2, Z1=W1   free: W0, D
    gemm_bt<1><<<g1, gblk, 0, stream>>>(W0, W1, W2, nullptr, nullptr);
    // iter 2: T2 = f(Z1*Y1) -> W0                          live: Y1=W2, Z1=W1, T2=W0   free: D
    gemm_bt<0><<<g1, gblk, 0, stream>>>(W1, W2, W0, nullptr, nullptr);
    //   Y2 = Y1*T2 -> D   (reads W2,W0)                    live: Z1=W1, T2=W0, Y2=D    free: W2
    gemm_bt<1><<<g1, gblk, 0, stream>>>(W2, W0, D, nullptr, nullptr);
    //   Z2 = T2*Z1 -> W2  (reads W0,W1)                    live: Y2=D, Z2=W2           free: W0, W1
    gemm_bt<1><<<g1, gblk, 0, stream>>>(W0, W1, W2, nullptr, nullptr);
    // iter 3: T3 = f(Z2*Y2) -> W0                          live: Y2=D, Z2=W2, T3=W0    free: W1
    gemm_bt<0><<<g1, gblk, 0, stream>>>(W2, D, W0, nullptr, nullptr);
    //   merged: Y3 = Y2*T3 -> W1 ; Z3 = T3*Z2 -> ... needs 2nd free! Y2=D dies after this dispatch.
    //   reads {D,W0,W2}, writes {W1, +1}. Only W1 free -> NOT mergeable here either with 4 slots.
    //   With 4 slots, merge is only possible if Y'/Z' overwrite dying operands -- they can't (same dispatch).
    //   => keep singles (Y frees its A-operand for Z's output):
    gemm_bt<1><<<g1, gblk, 0, stream>>>(D, W0, W1, nullptr, nullptr);   // Y3 -> W1 (Y2=D dead now)
    gemm_bt<1><<<g1, gblk, 0, stream>>>(W0, W2, D, nullptr, nullptr);   // Z3 = T3*Z2 -> D
    // iter 4: T4 = f(Z3*Y3) -> W0                          live: Y3=W1, Z3=D, T4=W0    free: W2
    gemm_bt<0><<<g1, gblk, 0, stream>>>(D, W1, W0, nullptr, nullptr);
    gemm_bt<1><<<g1, gblk, 0, stream>>>(W1, W0, W2, nullptr, nullptr);  // Y4 -> W2 (Y3=W1 dead)
    gemm_bt<1><<<g1, gblk, 0, stream>>>(W0, D, W1, nullptr, nullptr);   // Z4 = T4*Z3 -> W1
    // iter 5: T5 = f(Z4*Y4) -> W0 ; out = Y4*T5*sqrt(n) -> d_out (fp32)
    gemm_bt<0><<<g1, gblk, 0, stream>>>(W1, W2, W0, nullptr, nullptr);
    gemm_bt<2><<<g1, gblk, 0, stream>>>(W2, W0, nullptr, out, norms);
}

// Round 6
// 837.232 us; speedup vs baseline: 1.7287x; 1.0202x over previous
//
#include <hip/hip_runtime.h>
#include <hip/hip_bf16.h>
#include <stdint.h>

#define DIM   512
#define BATCH 64
#define KENC  1024          // encoded row: [hi(512) | lo(512)]
#define BM    256
#define BN    256
#define BKT   32
#define NKT   16
#define BUFE  32768         // ushorts per LDS buffer (64 KB): 4 planes * 8192

typedef __attribute__((ext_vector_type(8))) short short8;
typedef __attribute__((ext_vector_type(4))) float floatx4;

__device__ __forceinline__ ushort f2bf(float f) {
    __hip_bfloat16 h = __float2bfloat16(f);
    return *(ushort*)&h;
}
__device__ __forceinline__ float bf2f(ushort u) {
    __hip_bfloat16 h = *(__hip_bfloat16*)&u;
    return (float)h;
}

typedef __attribute__((address_space(3))) uint32_t lds_u32;
typedef const __attribute__((address_space(1))) uint32_t glb_u32;
__device__ __forceinline__ void gload16(const ushort* g, ushort* l) {
    __builtin_amdgcn_global_load_lds((glb_u32*)g, (lds_u32*)l, 16, 0, 0);
}

__global__ __launch_bounds__(256) void norm_partial_kernel(const float* __restrict__ x,
                                                           float* __restrict__ partial) {
    int b = blockIdx.y;
    int i = blockIdx.x;
    const float4* xv = (const float4*)(x + (size_t)b * DIM * DIM + (size_t)i * (DIM * DIM / 16));
    float s = 0.f;
    #pragma unroll
    for (int r = 0; r < 16; ++r) {
        float4 v = xv[r * 256 + threadIdx.x];
        s += v.x * v.x + v.y * v.y + v.z * v.z + v.w * v.w;
    }
    #pragma unroll
    for (int off = 32; off > 0; off >>= 1) s += __shfl_down(s, off, 64);
    __shared__ float red[4];
    int lane = threadIdx.x & 63, wid = threadIdx.x >> 6;
    if (lane == 0) red[wid] = s;
    __syncthreads();
    if (threadIdx.x == 0) partial[b * 16 + i] = red[0] + red[1] + red[2] + red[3];
}

__global__ __launch_bounds__(256) void init_kernel(const float* __restrict__ x,
                                                   const float* __restrict__ partial,
                                                   float* __restrict__ norms,
                                                   ushort* __restrict__ Yenc,
                                                   ushort* __restrict__ Tenc) {
    int b = blockIdx.y;
    float s = 0.f;
    #pragma unroll
    for (int p = 0; p < 16; ++p) s += partial[b * 16 + p];
    float nrm = sqrtf(s);
    if (blockIdx.x == 0 && threadIdx.x == 0) norms[b] = nrm;
    float inv = 1.0f / nrm;
    int idx = (blockIdx.x * 256 + threadIdx.x) * 4;
    int r = idx >> 9;
    int c = idx & 511;
    float4 v = *(const float4*)(x + (size_t)b * DIM * DIM + idx);
    float yv[4] = {v.x * inv, v.y * inv, v.z * inv, v.w * inv};
    size_t base = (size_t)b * DIM * KENC + (size_t)r * KENC;
    ushort yhi[4], ylo[4], thi[4], tlo[4];
    #pragma unroll
    for (int j = 0; j < 4; ++j) {
        float y = yv[j];
        yhi[j] = f2bf(y);
        ylo[j] = f2bf(y - bf2f(yhi[j]));
        float t = ((c + j) == r ? 1.5f : 0.0f) - 0.5f * y;
        thi[j] = f2bf(t);
        tlo[j] = f2bf(t - bf2f(thi[j]));
    }
    *(ushort4*)(Yenc + base + c)       = *(ushort4*)yhi;
    *(ushort4*)(Yenc + base + 512 + c) = *(ushort4*)ylo;
    *(ushort4*)(Tenc + base + c)       = *(ushort4*)thi;
    *(ushort4*)(Tenc + base + 512 + c) = *(ushort4*)tlo;
}

// stage one K-tile (all 4 planes: Ahi, Alo, Bhi, Blo) into LDS buffer.
// plane layout: 256 rows * 32 elem; physical chunk pc of row r holds logical
// chunk pc ^ ((r>>1)&3). LDS dest = base + tid*16B (lane-ordered, DMA-legal).
__device__ __forceinline__ void stage_tile(ushort* buf, const ushort* Ag, const ushort* Bg,
                                           int k0, int tid) {
    int row = tid >> 2;
    int pc  = tid & 3;
    int kc  = ((pc ^ ((row >> 1) & 3)) << 3);
    const ushort* ar = Ag + (size_t)row * KENC + k0 + kc;
    const ushort* br = Bg + (size_t)row * KENC + k0 + kc;
    gload16(ar,       &buf[tid * 8]);            // Ahi
    gload16(ar + 512, &buf[8192 + tid * 8]);     // Alo
    gload16(br,       &buf[16384 + tid * 8]);    // Bhi
    gload16(br + 512, &buf[24576 + tid * 8]);    // Blo
}

// 3 split-products on one staged tile: hi*hi + hi*lo + lo*hi (lo*lo dropped)
__device__ __forceinline__ void compute_tile(const ushort* buf, floatx4 (&acc)[4][4],
                                             int wrow, int wcol, int lane15, int fo) {
    const ushort* Ash = buf;
    const ushort* Asl = buf + 8192;
    const ushort* Bsh = buf + 16384;
    const ushort* Bsl = buf + 24576;
    short8 ah[4], bh[4], xl[4];
    #pragma unroll
    for (int i = 0; i < 4; ++i)
        ah[i] = *(const short8*)&Ash[(wrow + i * 16 + lane15) * BKT + fo];
    #pragma unroll
    for (int j = 0; j < 4; ++j)
        bh[j] = *(const short8*)&Bsh[(wcol + j * 16 + lane15) * BKT + fo];
    #pragma unroll
    for (int i = 0; i < 4; ++i)
        #pragma unroll
        for (int j = 0; j < 4; ++j)
            acc[i][j] = __builtin_amdgcn_mfma_f32_16x16x32_bf16(ah[i], bh[j], acc[i][j], 0, 0, 0);
    #pragma unroll
    for (int j = 0; j < 4; ++j)
        xl[j] = *(const short8*)&Bsl[(wcol + j * 16 + lane15) * BKT + fo];
    #pragma unroll
    for (int i = 0; i < 4; ++i)
        #pragma unroll
        for (int j = 0; j < 4; ++j)
            acc[i][j] = __builtin_amdgcn_mfma_f32_16x16x32_bf16(ah[i], xl[j], acc[i][j], 0, 0, 0);
    #pragma unroll
    for (int i = 0; i < 4; ++i)
        xl[i] = *(const short8*)&Asl[(wrow + i * 16 + lane15) * BKT + fo];
    #pragma unroll
    for (int i = 0; i < 4; ++i)
        #pragma unroll
        for (int j = 0; j < 4; ++j)
            acc[i][j] = __builtin_amdgcn_mfma_f32_16x16x32_bf16(xl[i], bh[j], acc[i][j], 0, 0, 0);
}

__device__ __forceinline__ void store_enc(ushort* Cenc, size_t matoff, int gr, int gc, float v) {
    ushort hi = f2bf(v);
    ushort lo = f2bf(v - bf2f(hi));
    Cenc[matoff + (size_t)gr * KENC + gc] = hi;
    Cenc[matoff + (size_t)gr * KENC + 512 + gc] = lo;
}

// 256x256 tile, 1024 threads (16 waves, each a 64x64 quadrant), double-buffered LDS.
// MODE 0: T-enc = 1.5I - 0.5*C   MODE 1: C-enc   MODE 2: fp32 C*sqrt(normA)
template <int MODE>
__global__ __launch_bounds__(1024, 4) void gemm_bt(const ushort* __restrict__ A,
                                                   const ushort* __restrict__ B,
                                                   ushort* __restrict__ Cenc,
                                                   float* __restrict__ Cout,
                                                   const float* __restrict__ norms) {
    __shared__ __attribute__((aligned(16))) ushort sm[2 * BUFE];  // 128 KB

    int f = blockIdx.x;           // 256 blocks: 64 matrices x 4 quadrant-tiles
    int xcd = f & 7;
    int g   = f >> 3;             // 0..31
    int b   = xcd + 8 * (g >> 2); // 8 matrices per XCD (4 co-tiles each)
    int t   = g & 3;
    int bm  = t >> 1;
    int bn  = t & 1;

    size_t matoff = (size_t)b * DIM * KENC;
    const ushort* Ag = A + matoff + (size_t)bm * BM * KENC;
    const ushort* Bg = B + matoff + (size_t)bn * BN * KENC;

    int tid = threadIdx.x;
    int wave = tid >> 6, lane = tid & 63;
    int lane15 = lane & 15, quad = lane >> 4;
    int wrow = (wave >> 2) * 64, wcol = (wave & 3) * 64;
    int s2 = (lane15 >> 1) & 3;
    int fo = ((quad ^ s2) << 3);

    floatx4 acc[4][4];
    #pragma unroll
    for (int i = 0; i < 4; ++i)
        #pragma unroll
        for (int j = 0; j < 4; ++j)
            acc[i][j] = (floatx4){0.f, 0.f, 0.f, 0.f};

    stage_tile(sm, Ag, Bg, 0, tid);
    for (int kt = 0; kt < NKT; ++kt) {
        ushort* cur = sm + (kt & 1) * BUFE;
        ushort* nxt = sm + ((kt + 1) & 1) * BUFE;
        __syncthreads();   // vmcnt drain: stage(kt) landed; lgkm: prior reads of nxt done
        if (kt + 1 < NKT) stage_tile(nxt, Ag, Bg, (kt + 1) * BKT, tid);  // prefetch overlaps compute
        compute_tile(cur, acc, wrow, wcol, lane15, fo);
    }

    float scale = (MODE == 2) ? sqrtf(norms[b]) : 0.f;
    #pragma unroll
    for (int i = 0; i < 4; ++i) {
        int gr0 = bm * BM + wrow + i * 16 + quad * 4;
        #pragma unroll
        for (int j = 0; j < 4; ++j) {
            int gc = bn * BN + wcol + j * 16 + lane15;
            #pragma unroll
            for (int rr = 0; rr < 4; ++rr) {
                int gr = gr0 + rr;
                float cv = acc[i][j][rr];
                if (MODE == 0) {
                    store_enc(Cenc, matoff, gr, gc, (gr == gc ? 1.5f : 0.0f) - 0.5f * cv);
                } else if (MODE == 1) {
                    store_enc(Cenc, matoff, gr, gc, cv);
                } else {
                    Cout[(size_t)b * DIM * DIM + (size_t)gr * DIM + gc] = cv * scale;
                }
            }
        }
    }
}

extern "C" void kernel_launch(void* const* d_in, const int* in_sizes, int n_in,
                              void* d_out, int out_size, void* d_ws, size_t ws_size,
                              hipStream_t stream) {
    const float* x = (const float*)d_in[0];  // d_in[1] = I, unused
    float* out = (float*)d_out;

    const size_t MATB = (size_t)BATCH * DIM * KENC * sizeof(ushort);  // 64 MB
    char* ws = (char*)d_ws;
    ushort* W0 = (ushort*)(ws + 0 * MATB);
    ushort* W1 = (ushort*)(ws + 1 * MATB);
    ushort* W2 = (ushort*)(ws + 2 * MATB);
    float* partial = (float*)(ws + 3 * MATB);          // 192 MB + 4 KB total
    float* norms   = (float*)(ws + 3 * MATB + 4096);
    ushort* D = (ushort*)d_out;  // encoded scratch slot #4; final fp32 GEMM overwrites last

    dim3 gblk(1024);
    dim3 g1(256);

    norm_partial_kernel<<<dim3(16, BATCH), 256, 0, stream>>>(x, partial);
    init_kernel<<<dim3(256, BATCH), 256, 0, stream>>>(x, partial, norms, W0, W1);  // Y0->W0, T1(=Z1)->W1

    // iter 1: Y1 = Y0*T1 -> W2 ; Z1 = T1 (W1).             live: Y1=W2, Z1=W1   free: W0, D
    gemm_bt<1><<<g1, gblk, 0, stream>>>(W0, W1, W2, nullptr, nullptr);
    // iter 2: T2 = f(Z1*Y1) -> W0                          live: Y1=W2, Z1=W1, T2=W0   free: D
    gemm_bt<0><<<g1, gblk, 0, stream>>>(W1, W2, W0, nullptr, nullptr);
    gemm_bt<1><<<g1, gblk, 0, stream>>>(W2, W0, D, nullptr, nullptr);   // Y2 -> D
    gemm_bt<1><<<g1, gblk, 0, stream>>>(W0, W1, W2, nullptr, nullptr);  // Z2 = T2*Z1 -> W2
    // iter 3
    gemm_bt<0><<<g1, gblk, 0, stream>>>(W2, D, W0, nullptr, nullptr);   // T3 -> W0
    gemm_bt<1><<<g1, gblk, 0, stream>>>(D, W0, W1, nullptr, nullptr);   // Y3 -> W1
    gemm_bt<1><<<g1, gblk, 0, stream>>>(W0, W2, D, nullptr, nullptr);   // Z3 = T3*Z2 -> D
    // iter 4
    gemm_bt<0><<<g1, gblk, 0, stream>>>(D, W1, W0, nullptr, nullptr);   // T4 -> W0
    gemm_bt<1><<<g1, gblk, 0, stream>>>(W1, W0, W2, nullptr, nullptr);  // Y4 -> W2
    gemm_bt<1><<<g1, gblk, 0, stream>>>(W0, D, W1, nullptr, nullptr);   // Z4 = T4*Z3 -> W1
    // iter 5
    gemm_bt<0><<<g1, gblk, 0, stream>>>(W1, W2, W0, nullptr, nullptr);  // T5 -> W0
    gemm_bt<2><<<g1, gblk, 0, stream>>>(W2, W0, nullptr, out, norms);   // out = Y4*T5*sqrt(n)
}